// Round 1
// baseline (694.315 us; speedup 1.0000x reference)
//
#include <hip/hip_runtime.h>
#include <hip/hip_bf16.h>
#include <cstdint>

using short8 = __attribute__((ext_vector_type(8))) short;
using f32x4  = __attribute__((ext_vector_type(4))) float;

constexpr int BN = 4, HN = 4, SN = 4096, DN = 256, HD = 64;
constexpr float SCALE = 0.125f;   // 1/sqrt(64)
constexpr int QB = 64, KVB = 32;  // q rows per block (16/wave), kv tile

__device__ __forceinline__ unsigned short f2bf(float x) {
  union { float f; unsigned int u; } c; c.f = x;
  unsigned int u = c.u;
  return (unsigned short)((u + 0x7fffu + ((u >> 16) & 1u)) >> 16);
}
__device__ __forceinline__ float bf2f(unsigned short h) {
  union { unsigned int u; float f; } c; c.u = ((unsigned int)h) << 16;
  return c.f;
}

// ---------------- QKV projection: q,k,v = x @ W{q,k,v}.T, fp32 acc, bf16 out
// out layout: [B, H, S, HD]  (head-major for attention)
__global__ __launch_bounds__(256) void qkv_kernel(
    const float* __restrict__ x,
    const float* __restrict__ Wq, const float* __restrict__ Wk,
    const float* __restrict__ Wv,
    unsigned short* __restrict__ Qw, unsigned short* __restrict__ Kw,
    unsigned short* __restrict__ Vw) {
  __shared__ float xs[8][DN];
  const int t = threadIdx.x;
  const long g0 = (long)blockIdx.x * 8;  // first (b,s) row
#pragma unroll
  for (int r = 0; r < 8; ++r) xs[r][t] = x[(g0 + r) * DN + t];
  __syncthreads();
  float aq[8], ak[8], av[8];
#pragma unroll
  for (int r = 0; r < 8; ++r) { aq[r] = 0.f; ak[r] = 0.f; av[r] = 0.f; }
  const float4* wqp = (const float4*)(Wq + (long)t * DN);
  const float4* wkp = (const float4*)(Wk + (long)t * DN);
  const float4* wvp = (const float4*)(Wv + (long)t * DN);
  for (int c = 0; c < DN / 4; ++c) {
    float4 wq = wqp[c], wk = wkp[c], wv = wvp[c];
#pragma unroll
    for (int r = 0; r < 8; ++r) {
      float4 xv = *(const float4*)&xs[r][c * 4];
      aq[r] += wq.x * xv.x + wq.y * xv.y + wq.z * xv.z + wq.w * xv.w;
      ak[r] += wk.x * xv.x + wk.y * xv.y + wk.z * xv.z + wk.w * xv.w;
      av[r] += wv.x * xv.x + wv.y * xv.y + wv.z * xv.z + wv.w * xv.w;
    }
  }
  const int h = t >> 6, hd = t & 63;
#pragma unroll
  for (int r = 0; r < 8; ++r) {
    long grow = g0 + r;
    int b = (int)(grow >> 12), s = (int)(grow & 4095);
    long idx = ((long)(b * HN + h) * SN + s) * HD + hd;
    Qw[idx] = f2bf(aq[r]);
    Kw[idx] = f2bf(ak[r]);
    Vw[idx] = f2bf(av[r]);
  }
}

// ---------------- flash attention, causal. 1 block = 4 waves = 64 q rows.
__global__ __launch_bounds__(256) void attn_kernel(
    const unsigned short* __restrict__ Qw, const unsigned short* __restrict__ Kw,
    const unsigned short* __restrict__ Vw, unsigned short* __restrict__ Ow) {
  __shared__ __align__(16) unsigned short VT[64][40];      // V^T, padded rows
  __shared__ __align__(16) unsigned short Pl[4][16][40];   // per-wave P tile

  const int tid = threadIdx.x;
  const int w = tid >> 6, lane = tid & 63;
  const int lo = lane & 15, hi = lane >> 4;
  const int nqb = SN / QB;                 // 64
  const int bid = blockIdx.x;
  const int bh = bid & 15;                 // b*H + h
  const int qb = (nqb - 1) - (bid >> 4);   // heavy q-blocks dispatched first
  const int q0 = qb * QB;
  const int qw = q0 + w * 16;              // this wave's q base
  const long base = (long)bh * SN * HD;

  // Q fragments: A[m=q(lo)][k=hd], 2 chunks of 32 hd
  short8 qf[2];
#pragma unroll
  for (int c = 0; c < 2; ++c)
    qf[c] = *(const short8*)(Qw + base + (long)(qw + lo) * HD + c * 32 + hi * 8);

  f32x4 oacc[4];
#pragma unroll
  for (int n = 0; n < 4; ++n)
#pragma unroll
    for (int e = 0; e < 4; ++e) oacc[n][e] = 0.f;
  float m_[4], l_[4];
#pragma unroll
  for (int r = 0; r < 4; ++r) { m_[r] = -INFINITY; l_[r] = 0.f; }

  const int nt = q0 / KVB + 2;  // kv tiles needed to cover q0+63
  for (int kt = 0; kt < nt; ++kt) {
    const int k0 = kt * KVB;
    // stage V^T: 256 threads, each 8 contiguous bf16 of one V row
    {
      const int key = tid & 31;
      const int hp = (tid >> 5) * 8;
      short8 v8 = *(const short8*)(Vw + base + (long)(k0 + key) * HD + hp);
#pragma unroll
      for (int j = 0; j < 8; ++j) VT[hp + j][key] = (unsigned short)v8[j];
    }
    __syncthreads();

    if (k0 <= qw + 15) {  // wave has unmasked work in this tile
      // ---- QK^T : scores [16 q x 32 keys], fp32 acc
      f32x4 sc[2];
#pragma unroll
      for (int tt = 0; tt < 2; ++tt)
#pragma unroll
        for (int e = 0; e < 4; ++e) sc[tt][e] = 0.f;
#pragma unroll
      for (int tt = 0; tt < 2; ++tt) {
#pragma unroll
        for (int c = 0; c < 2; ++c) {
          short8 kf = *(const short8*)(Kw + base +
                          (long)(k0 + tt * 16 + lo) * HD + c * 32 + hi * 8);
          sc[tt] = __builtin_amdgcn_mfma_f32_16x16x32_bf16(qf[c], kf, sc[tt], 0, 0, 0);
        }
      }
      // ---- mask + scale; acc layout: col(key)=lo, row(q)=4*hi+r
      float p0v[4], p1v[4], mx[4];
#pragma unroll
      for (int r = 0; r < 4; ++r) {
        const int q = qw + hi * 4 + r;
        float s0 = sc[0][r] * SCALE;
        float s1 = sc[1][r] * SCALE;
        if (k0 + lo > q) s0 = -INFINITY;
        if (k0 + 16 + lo > q) s1 = -INFINITY;
        p0v[r] = s0; p1v[r] = s1;
        mx[r] = fmaxf(s0, s1);
      }
#pragma unroll
      for (int d = 1; d < 16; d <<= 1)
#pragma unroll
        for (int r = 0; r < 4; ++r) mx[r] = fmaxf(mx[r], __shfl_xor(mx[r], d, 64));
      float alpha[4], rs[4];
#pragma unroll
      for (int r = 0; r < 4; ++r) {
        float mn = fmaxf(m_[r], mx[r]);
        alpha[r] = __expf(m_[r] - mn);
        m_[r] = mn;
        float e0 = __expf(p0v[r] - mn);
        float e1 = __expf(p1v[r] - mn);
        p0v[r] = e0; p1v[r] = e1;
        rs[r] = e0 + e1;
      }
#pragma unroll
      for (int d = 1; d < 16; d <<= 1)
#pragma unroll
        for (int r = 0; r < 4; ++r) rs[r] += __shfl_xor(rs[r], d, 64);
#pragma unroll
      for (int r = 0; r < 4; ++r) l_[r] = l_[r] * alpha[r] + rs[r];
#pragma unroll
      for (int n = 0; n < 4; ++n)
#pragma unroll
        for (int r = 0; r < 4; ++r) oacc[n][r] *= alpha[r];
      // ---- P -> LDS (bf16), then PV
#pragma unroll
      for (int r = 0; r < 4; ++r) {
        Pl[w][hi * 4 + r][lo]      = f2bf(p0v[r]);
        Pl[w][hi * 4 + r][16 + lo] = f2bf(p1v[r]);
      }
      asm volatile("s_waitcnt lgkmcnt(0)" ::: "memory");
      short8 pa = *(const short8*)&Pl[w][lo][hi * 8];  // A[m=q][k=key]
#pragma unroll
      for (int n = 0; n < 4; ++n) {
        short8 vb = *(const short8*)&VT[n * 16 + lo][hi * 8];  // B[k=key][n=hd]
        oacc[n] = __builtin_amdgcn_mfma_f32_16x16x32_bf16(pa, vb, oacc[n], 0, 0, 0);
      }
    }
    __syncthreads();
  }
  // ---- epilogue: O/l, write [B,S,D] bf16
  const int b = bh >> 2, h = bh & 3;
#pragma unroll
  for (int n = 0; n < 4; ++n) {
#pragma unroll
    for (int r = 0; r < 4; ++r) {
      int q = qw + hi * 4 + r;
      float val = oacc[n][r] / l_[r];
      Ow[((long)(b * SN + q)) * DN + h * HD + n * 16 + lo] = f2bf(val);
    }
  }
}

// ---------------- output projection: out = O @ Wo.T (fp32 out)
__global__ __launch_bounds__(256) void oproj_kernel(
    const unsigned short* __restrict__ Ow, const float* __restrict__ Wo,
    float* __restrict__ out) {
  __shared__ float os[8][DN];
  const int t = threadIdx.x;
  const long g0 = (long)blockIdx.x * 8;
#pragma unroll
  for (int r = 0; r < 8; ++r) os[r][t] = bf2f(Ow[(g0 + r) * DN + t]);
  __syncthreads();
  float acc[8];
#pragma unroll
  for (int r = 0; r < 8; ++r) acc[r] = 0.f;
  const float4* wop = (const float4*)(Wo + (long)t * DN);
  for (int c = 0; c < DN / 4; ++c) {
    float4 wv = wop[c];
#pragma unroll
    for (int r = 0; r < 8; ++r) {
      float4 xv = *(const float4*)&os[r][c * 4];
      acc[r] += wv.x * xv.x + wv.y * xv.y + wv.z * xv.z + wv.w * xv.w;
    }
  }
#pragma unroll
  for (int r = 0; r < 8; ++r) out[(g0 + r) * DN + t] = acc[r];
}

extern "C" void kernel_launch(void* const* d_in, const int* in_sizes, int n_in,
                              void* d_out, int out_size, void* d_ws, size_t ws_size,
                              hipStream_t stream) {
  const float* x  = (const float*)d_in[0];
  const float* Wq = (const float*)d_in[1];
  const float* Wk = (const float*)d_in[2];
  const float* Wv = (const float*)d_in[3];
  const float* Wo = (const float*)d_in[4];
  float* out = (float*)d_out;

  const size_t per = (size_t)BN * HN * SN * HD;  // 4,194,304 elems
  unsigned short* Qw = (unsigned short*)d_ws;
  unsigned short* Kw = Qw + per;
  unsigned short* Vw = Kw + per;
  unsigned short* Ow = Vw + per;  // [B,S,D] bf16

  qkv_kernel<<<BN * SN / 8, 256, 0, stream>>>(x, Wq, Wk, Wv, Qw, Kw, Vw);
  attn_kernel<<<(BN * HN) * (SN / QB), 256, 0, stream>>>(Qw, Kw, Vw, Ow);
  oproj_kernel<<<BN * SN / 8, 256, 0, stream>>>(Ow, Wo, out);
}

// Round 2
// 281.989 us; speedup vs baseline: 2.4622x; 2.4622x over previous
//
#include <hip/hip_runtime.h>
#include <hip/hip_bf16.h>
#include <cstdint>

using short8  = __attribute__((ext_vector_type(8))) short;
using u16x8   = __attribute__((ext_vector_type(8))) unsigned short;
using u16x4   = __attribute__((ext_vector_type(4))) unsigned short;
using f32x4   = __attribute__((ext_vector_type(4))) float;

constexpr int BN = 4, HN = 4, SN = 4096, DN = 256, HD = 64;
constexpr int MROWS = BN * SN;  // 16384
constexpr float SCALE = 0.125f; // 1/sqrt(64)
constexpr int QB = 64, KVB = 32;

__device__ __forceinline__ unsigned short f2bf(float x) {
  union { float f; unsigned int u; } c; c.f = x;
  unsigned int u = c.u;
  return (unsigned short)((u + 0x7fffu + ((u >> 16) & 1u)) >> 16);
}
__device__ __forceinline__ float bf2f(unsigned short h) {
  union { unsigned int u; float f; } c; c.u = ((unsigned int)h) << 16;
  return c.f;
}

#define GLDS16(g, l)                                                  \
  __builtin_amdgcn_global_load_lds(                                   \
      (const __attribute__((address_space(1))) void*)(g),             \
      (__attribute__((address_space(3))) void*)(l), 16, 0, 0)

// ---------------- fp32 -> bf16 conversion: x, Wq|Wk|Wv (concat), Wo
__global__ __launch_bounds__(256) void convert_kernel(
    const float* __restrict__ x,  const float* __restrict__ Wq,
    const float* __restrict__ Wk, const float* __restrict__ Wv,
    const float* __restrict__ Wo,
    unsigned short* __restrict__ xb, unsigned short* __restrict__ Wcat,
    unsigned short* __restrict__ Wob) {
  const long NX4 = (long)MROWS * DN / 4;  // 1,048,576 float4s
  const long NW4 = 65536 / 4;             // per weight matrix
  const long total = NX4 + 4 * NW4;
  for (long i = (long)blockIdx.x * 256 + threadIdx.x; i < total;
       i += (long)gridDim.x * 256) {
    const float* src; unsigned short* dst;
    if (i < NX4) { src = x + i * 4; dst = xb + i * 4; }
    else {
      long j = i - NX4; int w = (int)(j >> 14); long o = (j & 16383) * 4;
      src = (w == 0 ? Wq : w == 1 ? Wk : w == 2 ? Wv : Wo) + o;
      dst = (w < 3 ? Wcat + (long)w * 65536 : Wob) + o;
    }
    float4 v = *(const float4*)src;
    u16x4 pk; pk[0] = f2bf(v.x); pk[1] = f2bf(v.y);
    pk[2] = f2bf(v.z); pk[3] = f2bf(v.w);
    *(u16x4*)dst = pk;
  }
}

// ---------------- bf16 MFMA GEMM: C[M][N] = A[M][K=256] * B[N][K=256]^T
// 128x128 tile, BK=32 double-buffered via global_load_lds, 4 waves 2x2.
// MODE 0: write q/k/v bf16 [B,H,S,HD]; MODE 1: write fp32 out [M][256].
template <int MODE, int NBN>
__global__ __launch_bounds__(256) void gemm_kernel(
    const unsigned short* __restrict__ Abf,  // [M][256]
    const unsigned short* __restrict__ Bbf,  // [Ntot][256]
    unsigned short* __restrict__ qo, unsigned short* __restrict__ ko,
    unsigned short* __restrict__ vo, float* __restrict__ out) {
  constexpr int SMEM = (MODE == 1) ? 128 * 132 * 4 : 128 * 136 * 2;
  __shared__ __align__(16) char smem[SMEM];
  unsigned short* stg = (unsigned short*)smem;  // [buf:2][A|B:4096 each]

  const int tid = threadIdx.x, lane = tid & 63, wid = tid >> 6;
  const int lo = lane & 15, hi = lane >> 4;
  const int bn = blockIdx.x % NBN, bm = blockIdx.x / NBN;
  const int wm = (wid >> 1) * 64, wn = (wid & 1) * 64;
  const long arow0 = (long)bm * 128, brow0 = (long)bn * 128;

  auto stage = [&](int buf, int kt) {
    const int row = (wid * 2) * 16 + (lane >> 2);   // +16 rows for issue 1
    const int col = (lane & 3) * 8;
    const unsigned short* ga = Abf + (arow0 + row) * DN + kt * 32 + col;
    const unsigned short* gb = Bbf + (brow0 + row) * DN + kt * 32 + col;
    unsigned short* la = stg + buf * 8192 + wid * 1024;
    unsigned short* lb = la + 4096;
    GLDS16(ga, la);
    GLDS16(ga + 16 * DN, la + 512);
    GLDS16(gb, lb);
    GLDS16(gb + 16 * DN, lb + 512);
  };

  f32x4 acc[4][4];  // [fn][fm]; swapped orientation: col=lo->m, row=hi*4+r->n
#pragma unroll
  for (int a = 0; a < 4; ++a)
#pragma unroll
    for (int b = 0; b < 4; ++b)
#pragma unroll
      for (int e = 0; e < 4; ++e) acc[a][b][e] = 0.f;

  stage(0, 0);
#pragma unroll
  for (int kt = 0; kt < 8; ++kt) {
    const int buf = kt & 1;
    __syncthreads();  // drains vmcnt for stage(buf); fences reads of buf^1
    if (kt < 7) stage(buf ^ 1, kt + 1);
    const unsigned short* sa = stg + buf * 8192;
    const unsigned short* sb = sa + 4096;
    short8 af[4], bf[4];
#pragma unroll
    for (int f = 0; f < 4; ++f) {
      af[f] = *(const short8*)(sa + (wm + f * 16 + lo) * 32 + hi * 8);
      bf[f] = *(const short8*)(sb + (wn + f * 16 + lo) * 32 + hi * 8);
    }
#pragma unroll
    for (int fn = 0; fn < 4; ++fn)
#pragma unroll
      for (int fm = 0; fm < 4; ++fm)
        acc[fn][fm] = __builtin_amdgcn_mfma_f32_16x16x32_bf16(
            bf[fn], af[fm], acc[fn][fm], 0, 0, 0);
  }
  __syncthreads();  // all reads done; reuse smem for C tile

  if constexpr (MODE == 0) {
    unsigned short* cs = (unsigned short*)smem;  // [128][136] bf16
#pragma unroll
    for (int fn = 0; fn < 4; ++fn)
#pragma unroll
      for (int fm = 0; fm < 4; ++fm) {
        u16x4 pk;
#pragma unroll
        for (int r = 0; r < 4; ++r) pk[r] = f2bf(acc[fn][fm][r]);
        const int m = wm + fm * 16 + lo, n0 = wn + fn * 16 + hi * 4;
        *(u16x4*)(cs + m * 136 + n0) = pk;
      }
    __syncthreads();
    unsigned short* dstmat = (bn < 2) ? qo : (bn < 4) ? ko : vo;
    const int colbase = (bn & 1) * 128;
#pragma unroll
    for (int p = 0; p < 8; ++p) {
      const int ml = p * 16 + (tid >> 4), n0 = (tid & 15) * 8;
      u16x8 v = *(u16x8*)(cs + ml * 136 + n0);
      const int c = colbase + n0, h = c >> 6, hd = c & 63;
      const long m = arow0 + ml;
      const int b = (int)(m >> 12), s = (int)(m & 4095);
      *(u16x8*)(dstmat + ((long)(b * HN + h) * SN + s) * HD + hd) = v;
    }
  } else {
    float* csf = (float*)smem;  // [128][132] fp32
#pragma unroll
    for (int fn = 0; fn < 4; ++fn)
#pragma unroll
      for (int fm = 0; fm < 4; ++fm) {
        const int m = wm + fm * 16 + lo, n0 = wn + fn * 16 + hi * 4;
        *(f32x4*)(csf + m * 132 + n0) = acc[fn][fm];
      }
    __syncthreads();
#pragma unroll
    for (int p = 0; p < 8; ++p) {
      const int ml = p * 16 + (tid >> 4), n0 = (tid & 15) * 8;
      f32x4 v0 = *(f32x4*)(csf + ml * 132 + n0);
      f32x4 v1 = *(f32x4*)(csf + ml * 132 + n0 + 4);
      float* dst = out + (arow0 + ml) * DN + bn * 128 + n0;
      *(f32x4*)dst = v0;
      *(f32x4*)(dst + 4) = v1;
    }
  }
}

// ---------------- flash attention, causal. 1 block = 4 waves = 64 q rows.
__global__ __launch_bounds__(256) void attn_kernel(
    const unsigned short* __restrict__ Qw, const unsigned short* __restrict__ Kw,
    const unsigned short* __restrict__ Vw, unsigned short* __restrict__ Ow) {
  __shared__ __align__(16) unsigned short VT[64][40];      // V^T, padded rows
  __shared__ __align__(16) unsigned short Pl[4][16][40];   // per-wave P tile

  const int tid = threadIdx.x;
  const int w = tid >> 6, lane = tid & 63;
  const int lo = lane & 15, hi = lane >> 4;
  const int nqb = SN / QB;                 // 64
  const int bid = blockIdx.x;
  const int bh = bid & 15;                 // b*H + h
  const int qb = (nqb - 1) - (bid >> 4);   // heavy q-blocks dispatched first
  const int q0 = qb * QB;
  const int qw = q0 + w * 16;              // this wave's q base
  const long base = (long)bh * SN * HD;

  short8 qf[2];
#pragma unroll
  for (int c = 0; c < 2; ++c)
    qf[c] = *(const short8*)(Qw + base + (long)(qw + lo) * HD + c * 32 + hi * 8);

  f32x4 oacc[4];
#pragma unroll
  for (int n = 0; n < 4; ++n)
#pragma unroll
    for (int e = 0; e < 4; ++e) oacc[n][e] = 0.f;
  float m_[4], l_[4];
#pragma unroll
  for (int r = 0; r < 4; ++r) { m_[r] = -INFINITY; l_[r] = 0.f; }

  const int nt = q0 / KVB + 2;
  for (int kt = 0; kt < nt; ++kt) {
    const int k0 = kt * KVB;
    {
      const int key = tid & 31;
      const int hp = (tid >> 5) * 8;
      short8 v8 = *(const short8*)(Vw + base + (long)(k0 + key) * HD + hp);
#pragma unroll
      for (int j = 0; j < 8; ++j) VT[hp + j][key] = (unsigned short)v8[j];
    }
    __syncthreads();

    if (k0 <= qw + 15) {
      f32x4 sc[2];
#pragma unroll
      for (int tt = 0; tt < 2; ++tt)
#pragma unroll
        for (int e = 0; e < 4; ++e) sc[tt][e] = 0.f;
#pragma unroll
      for (int tt = 0; tt < 2; ++tt) {
#pragma unroll
        for (int c = 0; c < 2; ++c) {
          short8 kf = *(const short8*)(Kw + base +
                          (long)(k0 + tt * 16 + lo) * HD + c * 32 + hi * 8);
          sc[tt] = __builtin_amdgcn_mfma_f32_16x16x32_bf16(qf[c], kf, sc[tt], 0, 0, 0);
        }
      }
      float p0v[4], p1v[4], mx[4];
#pragma unroll
      for (int r = 0; r < 4; ++r) {
        const int q = qw + hi * 4 + r;
        float s0 = sc[0][r] * SCALE;
        float s1 = sc[1][r] * SCALE;
        if (k0 + lo > q) s0 = -INFINITY;
        if (k0 + 16 + lo > q) s1 = -INFINITY;
        p0v[r] = s0; p1v[r] = s1;
        mx[r] = fmaxf(s0, s1);
      }
#pragma unroll
      for (int d = 1; d < 16; d <<= 1)
#pragma unroll
        for (int r = 0; r < 4; ++r) mx[r] = fmaxf(mx[r], __shfl_xor(mx[r], d, 64));
      float alpha[4], rs[4];
#pragma unroll
      for (int r = 0; r < 4; ++r) {
        float mn = fmaxf(m_[r], mx[r]);
        alpha[r] = __expf(m_[r] - mn);
        m_[r] = mn;
        float e0 = __expf(p0v[r] - mn);
        float e1 = __expf(p1v[r] - mn);
        p0v[r] = e0; p1v[r] = e1;
        rs[r] = e0 + e1;
      }
#pragma unroll
      for (int d = 1; d < 16; d <<= 1)
#pragma unroll
        for (int r = 0; r < 4; ++r) rs[r] += __shfl_xor(rs[r], d, 64);
#pragma unroll
      for (int r = 0; r < 4; ++r) l_[r] = l_[r] * alpha[r] + rs[r];
#pragma unroll
      for (int n = 0; n < 4; ++n)
#pragma unroll
        for (int r = 0; r < 4; ++r) oacc[n][r] *= alpha[r];
#pragma unroll
      for (int r = 0; r < 4; ++r) {
        Pl[w][hi * 4 + r][lo]      = f2bf(p0v[r]);
        Pl[w][hi * 4 + r][16 + lo] = f2bf(p1v[r]);
      }
      asm volatile("s_waitcnt lgkmcnt(0)" ::: "memory");
      short8 pa = *(const short8*)&Pl[w][lo][hi * 8];
#pragma unroll
      for (int n = 0; n < 4; ++n) {
        short8 vb = *(const short8*)&VT[n * 16 + lo][hi * 8];
        oacc[n] = __builtin_amdgcn_mfma_f32_16x16x32_bf16(pa, vb, oacc[n], 0, 0, 0);
      }
    }
    __syncthreads();
  }
  const int b = bh >> 2, h = bh & 3;
#pragma unroll
  for (int n = 0; n < 4; ++n) {
#pragma unroll
    for (int r = 0; r < 4; ++r) {
      int q = qw + hi * 4 + r;
      float val = oacc[n][r] / l_[r];
      Ow[((long)(b * SN + q)) * DN + h * HD + n * 16 + lo] = f2bf(val);
    }
  }
}

extern "C" void kernel_launch(void* const* d_in, const int* in_sizes, int n_in,
                              void* d_out, int out_size, void* d_ws, size_t ws_size,
                              hipStream_t stream) {
  const float* x  = (const float*)d_in[0];
  const float* Wq = (const float*)d_in[1];
  const float* Wk = (const float*)d_in[2];
  const float* Wv = (const float*)d_in[3];
  const float* Wo = (const float*)d_in[4];
  float* out = (float*)d_out;

  const size_t per = (size_t)MROWS * DN;  // 4,194,304 elems
  unsigned short* xb   = (unsigned short*)d_ws;
  unsigned short* Wcat = xb + per;          // 768x256
  unsigned short* Wob  = Wcat + 768 * 256;  // 256x256
  unsigned short* Qw   = Wob + 65536;
  unsigned short* Kw   = Qw + per;
  unsigned short* Vw   = Kw + per;
  unsigned short* Ow   = xb;  // alias: xb dead after qkv gemm

  convert_kernel<<<2048, 256, 0, stream>>>(x, Wq, Wk, Wv, Wo, xb, Wcat, Wob);
  gemm_kernel<0, 6><<<6 * (MROWS / 128), 256, 0, stream>>>(
      xb, Wcat, Qw, Kw, Vw, nullptr);
  attn_kernel<<<(BN * HN) * (SN / QB), 256, 0, stream>>>(Qw, Kw, Vw, Ow);
  gemm_kernel<1, 2><<<2 * (MROWS / 128), 256, 0, stream>>>(
      Ow, Wob, nullptr, nullptr, nullptr, out);
}

// Round 3
// 247.150 us; speedup vs baseline: 2.8093x; 1.1410x over previous
//
#include <hip/hip_runtime.h>
#include <hip/hip_bf16.h>
#include <cstdint>

using short8  = __attribute__((ext_vector_type(8))) short;
using u16x8   = __attribute__((ext_vector_type(8))) unsigned short;
using u16x4   = __attribute__((ext_vector_type(4))) unsigned short;
using f32x4   = __attribute__((ext_vector_type(4))) float;

constexpr int BN = 4, HN = 4, SN = 4096, DN = 256, HD = 64;
constexpr int MROWS = BN * SN;  // 16384
constexpr int KVB = 64;         // kv tile (keys per block iteration)

__device__ __forceinline__ unsigned short f2bf(float x) {
  union { float f; unsigned int u; } c; c.f = x;
  unsigned int u = c.u;
  return (unsigned short)((u + 0x7fffu + ((u >> 16) & 1u)) >> 16);
}
__device__ __forceinline__ unsigned int cvt_pk_bf16(float a, float b) {
  unsigned int r;
  asm("v_cvt_pk_bf16_f32 %0, %1, %2" : "=v"(r) : "v"(a), "v"(b));
  return r;  // low16 = bf16(a), high16 = bf16(b)
}

#define GLDS16(g, l)                                                  \
  __builtin_amdgcn_global_load_lds(                                   \
      (const __attribute__((address_space(1))) void*)(g),             \
      (__attribute__((address_space(3))) void*)(l), 16, 0, 0)

// ---------------- fp32 -> bf16 conversion: x, Wq|Wk|Wv (concat), Wo
__global__ __launch_bounds__(256) void convert_kernel(
    const float* __restrict__ x,  const float* __restrict__ Wq,
    const float* __restrict__ Wk, const float* __restrict__ Wv,
    const float* __restrict__ Wo,
    unsigned short* __restrict__ xb, unsigned short* __restrict__ Wcat,
    unsigned short* __restrict__ Wob) {
  const long NX4 = (long)MROWS * DN / 4;
  const long NW4 = 65536 / 4;
  const long total = NX4 + 4 * NW4;
  for (long i = (long)blockIdx.x * 256 + threadIdx.x; i < total;
       i += (long)gridDim.x * 256) {
    const float* src; unsigned short* dst;
    if (i < NX4) { src = x + i * 4; dst = xb + i * 4; }
    else {
      long j = i - NX4; int w = (int)(j >> 14); long o = (j & 16383) * 4;
      src = (w == 0 ? Wq : w == 1 ? Wk : w == 2 ? Wv : Wo) + o;
      dst = (w < 3 ? Wcat + (long)w * 65536 : Wob) + o;
    }
    float4 v = *(const float4*)src;
    u16x4 pk; pk[0] = f2bf(v.x); pk[1] = f2bf(v.y);
    pk[2] = f2bf(v.z); pk[3] = f2bf(v.w);
    *(u16x4*)dst = pk;
  }
}

// ---------------- bf16 MFMA GEMM: C[M][N] = A[M][K=256] * B[N][K=256]^T
// MODE 0: write q(*0.125)/k/v bf16 [B,H,S,HD]; MODE 1: write fp32 [M][256].
template <int MODE, int NBN>
__global__ __launch_bounds__(256) void gemm_kernel(
    const unsigned short* __restrict__ Abf,
    const unsigned short* __restrict__ Bbf,
    unsigned short* __restrict__ qo, unsigned short* __restrict__ ko,
    unsigned short* __restrict__ vo, float* __restrict__ out) {
  constexpr int SMEM = (MODE == 1) ? 128 * 132 * 4 : 128 * 136 * 2;
  __shared__ __align__(16) char smem[SMEM];
  unsigned short* stg = (unsigned short*)smem;

  const int tid = threadIdx.x, lane = tid & 63, wid = tid >> 6;
  const int lo = lane & 15, hi = lane >> 4;
  const int bn = blockIdx.x % NBN, bm = blockIdx.x / NBN;
  const int wm = (wid >> 1) * 64, wn = (wid & 1) * 64;
  const long arow0 = (long)bm * 128, brow0 = (long)bn * 128;

  auto stage = [&](int buf, int kt) {
    const int row = (wid * 2) * 16 + (lane >> 2);
    const int col = (lane & 3) * 8;
    const unsigned short* ga = Abf + (arow0 + row) * DN + kt * 32 + col;
    const unsigned short* gb = Bbf + (brow0 + row) * DN + kt * 32 + col;
    unsigned short* la = stg + buf * 8192 + wid * 1024;
    unsigned short* lb = la + 4096;
    GLDS16(ga, la);
    GLDS16(ga + 16 * DN, la + 512);
    GLDS16(gb, lb);
    GLDS16(gb + 16 * DN, lb + 512);
  };

  f32x4 acc[4][4];
#pragma unroll
  for (int a = 0; a < 4; ++a)
#pragma unroll
    for (int b = 0; b < 4; ++b)
#pragma unroll
      for (int e = 0; e < 4; ++e) acc[a][b][e] = 0.f;

  stage(0, 0);
#pragma unroll
  for (int kt = 0; kt < 8; ++kt) {
    const int buf = kt & 1;
    __syncthreads();
    if (kt < 7) stage(buf ^ 1, kt + 1);
    const unsigned short* sa = stg + buf * 8192;
    const unsigned short* sb = sa + 4096;
    short8 af[4], bf[4];
#pragma unroll
    for (int f = 0; f < 4; ++f) {
      af[f] = *(const short8*)(sa + (wm + f * 16 + lo) * 32 + hi * 8);
      bf[f] = *(const short8*)(sb + (wn + f * 16 + lo) * 32 + hi * 8);
    }
#pragma unroll
    for (int fn = 0; fn < 4; ++fn)
#pragma unroll
      for (int fm = 0; fm < 4; ++fm)
        acc[fn][fm] = __builtin_amdgcn_mfma_f32_16x16x32_bf16(
            bf[fn], af[fm], acc[fn][fm], 0, 0, 0);
  }
  __syncthreads();

  if constexpr (MODE == 0) {
    unsigned short* cs = (unsigned short*)smem;
    const float cscl = (bn < 2) ? 0.125f : 1.0f;  // pre-scale Q by 1/sqrt(HD)
#pragma unroll
    for (int fn = 0; fn < 4; ++fn)
#pragma unroll
      for (int fm = 0; fm < 4; ++fm) {
        u16x4 pk;
#pragma unroll
        for (int r = 0; r < 4; ++r) pk[r] = f2bf(acc[fn][fm][r] * cscl);
        const int m = wm + fm * 16 + lo, n0 = wn + fn * 16 + hi * 4;
        *(u16x4*)(cs + m * 136 + n0) = pk;
      }
    __syncthreads();
    unsigned short* dstmat = (bn < 2) ? qo : (bn < 4) ? ko : vo;
    const int colbase = (bn & 1) * 128;
#pragma unroll
    for (int p = 0; p < 8; ++p) {
      const int ml = p * 16 + (tid >> 4), n0 = (tid & 15) * 8;
      u16x8 v = *(u16x8*)(cs + ml * 136 + n0);
      const int c = colbase + n0, h = c >> 6, hd = c & 63;
      const long m = arow0 + ml;
      const int b = (int)(m >> 12), s = (int)(m & 4095);
      *(u16x8*)(dstmat + ((long)(b * HN + h) * SN + s) * HD + hd) = v;
    }
  } else {
    float* csf = (float*)smem;
#pragma unroll
    for (int fn = 0; fn < 4; ++fn)
#pragma unroll
      for (int fm = 0; fm < 4; ++fm) {
        const int m = wm + fm * 16 + lo, n0 = wn + fn * 16 + hi * 4;
        *(f32x4*)(csf + m * 132 + n0) = acc[fn][fm];
      }
    __syncthreads();
#pragma unroll
    for (int p = 0; p < 8; ++p) {
      const int ml = p * 16 + (tid >> 4), n0 = (tid & 15) * 8;
      f32x4 v0 = *(f32x4*)(csf + ml * 132 + n0);
      f32x4 v1 = *(f32x4*)(csf + ml * 132 + n0 + 4);
      float* dst = out + (arow0 + ml) * DN + bn * 128 + n0;
      *(f32x4*)dst = v0;
      *(f32x4*)(dst + 4) = v1;
    }
  }
}

// ---------------- flash attention, causal, KVB=64, swapped QK^T softmax.
// 1 block = 4 waves; wave w owns q rows [qw, qw+16). Q pre-scaled by 1/8.
__global__ __launch_bounds__(256) void attn_kernel(
    const unsigned short* __restrict__ Qw, const unsigned short* __restrict__ Kw,
    const unsigned short* __restrict__ Vw, unsigned short* __restrict__ Ow) {
  __shared__ __align__(16) unsigned short VT[2][64][72];   // V^T double-buffered
  __shared__ __align__(16) unsigned short Pl[4][16][72];   // per-wave P tile

  const int tid = threadIdx.x;
  const int w = tid >> 6, lane = tid & 63;
  const int lo = lane & 15, hi = lane >> 4;
  const int bid = blockIdx.x;
  const int bh = bid & 15;
  const int qb = 63 - (bid >> 4);          // heavy q-blocks dispatched first
  const int q0 = qb * 64;
  const int qw = q0 + w * 16;
  const long base = (long)bh * SN * HD;
  const int nt = qb + 1;                   // kv tiles (KVB == QB == 64)

  // Q fragments (B-operand: col=lo -> q row, k = hd)
  short8 qf[2];
#pragma unroll
  for (int c = 0; c < 2; ++c)
    qf[c] = *(const short8*)(Qw + base + (long)(qw + lo) * HD + c * 32 + hi * 8);

  f32x4 oacc[4];  // [n]: O[q=qw+4*hi+r][hd=n*16+lo]
#pragma unroll
  for (int n = 0; n < 4; ++n)
#pragma unroll
    for (int e = 0; e < 4; ++e) oacc[n][e] = 0.f;
  float m_ = -INFINITY, l_ = 0.f;  // softmax state for q = qw+lo

  // prologue: stage V tile 0 (wave w handles hd rows [16w,16w+16), key=lane)
  short8 vr0 = *(const short8*)(Vw + base + (long)lane * HD + w * 16);
  short8 vr1 = *(const short8*)(Vw + base + (long)lane * HD + w * 16 + 8);
#pragma unroll
  for (int j = 0; j < 8; ++j) {
    VT[0][w * 16 + j][lane]     = (unsigned short)vr0[j];
    VT[0][w * 16 + 8 + j][lane] = (unsigned short)vr1[j];
  }
  __syncthreads();

  for (int kt = 0; kt < nt; ++kt) {
    const int cur = kt & 1;
    const int k0 = kt * KVB;
    // T14: issue next V tile's global loads before this tile's compute
    if (kt + 1 < nt) {
      const long vb = base + (long)(k0 + KVB + lane) * HD + w * 16;
      vr0 = *(const short8*)(Vw + vb);
      vr1 = *(const short8*)(Vw + vb + 8);
    }

    // ---- QK^T swapped: sc[tt] C[row=key 16tt+4hi+r][col=q lo]
    f32x4 sc[4];
#pragma unroll
    for (int tt = 0; tt < 4; ++tt)
#pragma unroll
      for (int e = 0; e < 4; ++e) sc[tt][e] = 0.f;
#pragma unroll
    for (int tt = 0; tt < 4; ++tt)
#pragma unroll
      for (int c = 0; c < 2; ++c) {
        short8 kf = *(const short8*)(Kw + base +
                        (long)(k0 + tt * 16 + lo) * HD + c * 32 + hi * 8);
        sc[tt] = __builtin_amdgcn_mfma_f32_16x16x32_bf16(kf, qf[c], sc[tt], 0, 0, 0);
      }

    // ---- mask (only needed on the last tile: k0+63 > qw always there)
    if (k0 + 63 > qw) {
      const int kb = k0 + 4 * hi - qw - lo;  // key - q = kb + 16tt + r
#pragma unroll
      for (int tt = 0; tt < 4; ++tt)
#pragma unroll
        for (int r = 0; r < 4; ++r)
          if (kb + 16 * tt + r > 0) sc[tt][r] = -INFINITY;
    }

    // ---- row max: 15 in-reg + 2 shfl (q row = lanes {lo,lo+16,lo+32,lo+48})
    float mx;
    {
      f32x4 m4 = sc[0];
#pragma unroll
      for (int tt = 1; tt < 4; ++tt)
#pragma unroll
        for (int r = 0; r < 4; ++r) m4[r] = fmaxf(m4[r], sc[tt][r]);
      mx = fmaxf(fmaxf(m4[0], m4[1]), fmaxf(m4[2], m4[3]));
      mx = fmaxf(mx, __shfl_xor(mx, 16, 64));
      mx = fmaxf(mx, __shfl_xor(mx, 32, 64));
    }

    // ---- defer-max (T13, THR=8): rescale only when max grew materially
    if (__any(mx > m_ + 8.f)) {
      const float mn = fmaxf(m_, mx);
      const float alpha = __expf(m_ - mn);  // m_=-inf -> 0
      m_ = mn;
      l_ *= alpha;
#pragma unroll
      for (int r = 0; r < 4; ++r) {
        const float ar = __shfl(alpha, 4 * hi + r, 64);
#pragma unroll
        for (int n = 0; n < 4; ++n) oacc[n][r] *= ar;
      }
    }

    // ---- exp + row sum
    float p[16], rs = 0.f;
#pragma unroll
    for (int tt = 0; tt < 4; ++tt)
#pragma unroll
      for (int r = 0; r < 4; ++r) {
        float e = __expf(sc[tt][r] - m_);
        p[tt * 4 + r] = e;
        rs += e;
      }
    rs += __shfl_xor(rs, 16, 64);
    rs += __shfl_xor(rs, 32, 64);
    l_ += rs;

    // ---- P -> LDS (bf16, vectorized), keys 16tt+4hi+{0..3} for row lo
#pragma unroll
    for (int tt = 0; tt < 4; ++tt) {
      unsigned int w0 = cvt_pk_bf16(p[tt * 4 + 0], p[tt * 4 + 1]);
      unsigned int w1 = cvt_pk_bf16(p[tt * 4 + 2], p[tt * 4 + 3]);
      *(uint2*)&Pl[w][lo][tt * 16 + hi * 4] = make_uint2(w0, w1);
    }
    asm volatile("s_waitcnt lgkmcnt(0)" ::: "memory");

    // ---- PV: O += P[16q x 64k] * V^T
#pragma unroll
    for (int c = 0; c < 2; ++c) {
      short8 pa = *(const short8*)&Pl[w][lo][c * 32 + hi * 8];
#pragma unroll
      for (int n = 0; n < 4; ++n) {
        short8 vb = *(const short8*)&VT[cur][n * 16 + lo][c * 32 + hi * 8];
        oacc[n] = __builtin_amdgcn_mfma_f32_16x16x32_bf16(pa, vb, oacc[n], 0, 0, 0);
      }
    }

    // ---- stage next V tile into the other buffer
    if (kt + 1 < nt) {
#pragma unroll
      for (int j = 0; j < 8; ++j) {
        VT[cur ^ 1][w * 16 + j][lane]     = (unsigned short)vr0[j];
        VT[cur ^ 1][w * 16 + 8 + j][lane] = (unsigned short)vr1[j];
      }
    }
    __syncthreads();
  }

  // ---- epilogue
  const float rl = 1.f / l_;
  const int b = bh >> 2, h = bh & 3;
#pragma unroll
  for (int r = 0; r < 4; ++r) {
    const float rr = __shfl(rl, 4 * hi + r, 64);
    const int q = qw + 4 * hi + r;
#pragma unroll
    for (int n = 0; n < 4; ++n)
      Ow[((long)(b * SN + q)) * DN + h * HD + n * 16 + lo] = f2bf(oacc[n][r] * rr);
  }
}

extern "C" void kernel_launch(void* const* d_in, const int* in_sizes, int n_in,
                              void* d_out, int out_size, void* d_ws, size_t ws_size,
                              hipStream_t stream) {
  const float* x  = (const float*)d_in[0];
  const float* Wq = (const float*)d_in[1];
  const float* Wk = (const float*)d_in[2];
  const float* Wv = (const float*)d_in[3];
  const float* Wo = (const float*)d_in[4];
  float* out = (float*)d_out;

  const size_t per = (size_t)MROWS * DN;
  unsigned short* xb   = (unsigned short*)d_ws;
  unsigned short* Wcat = xb + per;
  unsigned short* Wob  = Wcat + 768 * 256;
  unsigned short* Qw   = Wob + 65536;
  unsigned short* Kw   = Qw + per;
  unsigned short* Vw   = Kw + per;
  unsigned short* Ow   = xb;  // alias: xb dead after qkv gemm

  convert_kernel<<<2048, 256, 0, stream>>>(x, Wq, Wk, Wv, Wo, xb, Wcat, Wob);
  gemm_kernel<0, 6><<<6 * (MROWS / 128), 256, 0, stream>>>(
      xb, Wcat, Qw, Kw, Vw, nullptr);
  attn_kernel<<<(BN * HN) * (SN / 64), 256, 0, stream>>>(Qw, Kw, Vw, Ow);
  gemm_kernel<1, 2><<<2 * (MROWS / 128), 256, 0, stream>>>(
      Ow, Wob, nullptr, nullptr, nullptr, out);
}

// Round 4
// 198.346 us; speedup vs baseline: 3.5005x; 1.2461x over previous
//
#include <hip/hip_runtime.h>
#include <hip/hip_bf16.h>
#include <cstdint>

using short8  = __attribute__((ext_vector_type(8))) short;
using u16x8   = __attribute__((ext_vector_type(8))) unsigned short;
using u16x4   = __attribute__((ext_vector_type(4))) unsigned short;
using f32x4   = __attribute__((ext_vector_type(4))) float;

constexpr int BN = 4, HN = 4, SN = 4096, DN = 256, HD = 64;
constexpr int MROWS = BN * SN;  // 16384
constexpr int KVB = 64;
// Q pre-scale: (1/sqrt(64)) * log2(e) -> scores land in exp2 domain
constexpr float QSCL = 0.18033688011112042f;

__device__ __forceinline__ unsigned short f2bf(float x) {
  union { float f; unsigned int u; } c; c.f = x;
  unsigned int u = c.u;
  return (unsigned short)((u + 0x7fffu + ((u >> 16) & 1u)) >> 16);
}
__device__ __forceinline__ unsigned int cvt_pk_bf16(float a, float b) {
  unsigned int r;
  asm("v_cvt_pk_bf16_f32 %0, %1, %2" : "=v"(r) : "v"(a), "v"(b));
  return r;  // low16 = bf16(a), high16 = bf16(b)
}

#define GLDS16(g, l)                                                  \
  __builtin_amdgcn_global_load_lds(                                   \
      (const __attribute__((address_space(1))) void*)(g),             \
      (__attribute__((address_space(3))) void*)(l), 16, 0, 0)

// ---------------- fp32 -> bf16 conversion: x, Wq|Wk|Wv (concat), Wo
__global__ __launch_bounds__(256) void convert_kernel(
    const float* __restrict__ x,  const float* __restrict__ Wq,
    const float* __restrict__ Wk, const float* __restrict__ Wv,
    const float* __restrict__ Wo,
    unsigned short* __restrict__ xb, unsigned short* __restrict__ Wcat,
    unsigned short* __restrict__ Wob) {
  const long NX4 = (long)MROWS * DN / 4;
  const long NW4 = 65536 / 4;
  const long total = NX4 + 4 * NW4;
  for (long i = (long)blockIdx.x * 256 + threadIdx.x; i < total;
       i += (long)gridDim.x * 256) {
    const float* src; unsigned short* dst;
    if (i < NX4) { src = x + i * 4; dst = xb + i * 4; }
    else {
      long j = i - NX4; int w = (int)(j >> 14); long o = (j & 16383) * 4;
      src = (w == 0 ? Wq : w == 1 ? Wk : w == 2 ? Wv : Wo) + o;
      dst = (w < 3 ? Wcat + (long)w * 65536 : Wob) + o;
    }
    float4 v = *(const float4*)src;
    u16x4 pk; pk[0] = f2bf(v.x); pk[1] = f2bf(v.y);
    pk[2] = f2bf(v.z); pk[3] = f2bf(v.w);
    *(u16x4*)dst = pk;
  }
}

// ---------------- bf16 MFMA GEMM: C[M][N] = A[M][K=256] * B[N][K=256]^T
// MODE 0: write q(*QSCL)/k/v bf16 [B,H,S,HD]; MODE 1: write fp32 [M][256].
template <int MODE, int NBN>
__global__ __launch_bounds__(256) void gemm_kernel(
    const unsigned short* __restrict__ Abf,
    const unsigned short* __restrict__ Bbf,
    unsigned short* __restrict__ qo, unsigned short* __restrict__ ko,
    unsigned short* __restrict__ vo, float* __restrict__ out) {
  constexpr int SMEM = (MODE == 1) ? 128 * 132 * 4 : 128 * 136 * 2;
  __shared__ __align__(16) char smem[SMEM];
  unsigned short* stg = (unsigned short*)smem;

  const int tid = threadIdx.x, lane = tid & 63, wid = tid >> 6;
  const int lo = lane & 15, hi = lane >> 4;
  const int bn = blockIdx.x % NBN, bm = blockIdx.x / NBN;
  const int wm = (wid >> 1) * 64, wn = (wid & 1) * 64;
  const long arow0 = (long)bm * 128, brow0 = (long)bn * 128;

  auto stage = [&](int buf, int kt) {
    const int row = (wid * 2) * 16 + (lane >> 2);
    const int col = (lane & 3) * 8;
    const unsigned short* ga = Abf + (arow0 + row) * DN + kt * 32 + col;
    const unsigned short* gb = Bbf + (brow0 + row) * DN + kt * 32 + col;
    unsigned short* la = stg + buf * 8192 + wid * 1024;
    unsigned short* lb = la + 4096;
    GLDS16(ga, la);
    GLDS16(ga + 16 * DN, la + 512);
    GLDS16(gb, lb);
    GLDS16(gb + 16 * DN, lb + 512);
  };

  f32x4 acc[4][4];
#pragma unroll
  for (int a = 0; a < 4; ++a)
#pragma unroll
    for (int b = 0; b < 4; ++b)
#pragma unroll
      for (int e = 0; e < 4; ++e) acc[a][b][e] = 0.f;

  stage(0, 0);
#pragma unroll
  for (int kt = 0; kt < 8; ++kt) {
    const int buf = kt & 1;
    __syncthreads();
    if (kt < 7) stage(buf ^ 1, kt + 1);
    const unsigned short* sa = stg + buf * 8192;
    const unsigned short* sb = sa + 4096;
    short8 af[4], bf[4];
#pragma unroll
    for (int f = 0; f < 4; ++f) {
      af[f] = *(const short8*)(sa + (wm + f * 16 + lo) * 32 + hi * 8);
      bf[f] = *(const short8*)(sb + (wn + f * 16 + lo) * 32 + hi * 8);
    }
#pragma unroll
    for (int fn = 0; fn < 4; ++fn)
#pragma unroll
      for (int fm = 0; fm < 4; ++fm)
        acc[fn][fm] = __builtin_amdgcn_mfma_f32_16x16x32_bf16(
            bf[fn], af[fm], acc[fn][fm], 0, 0, 0);
  }
  __syncthreads();

  if constexpr (MODE == 0) {
    unsigned short* cs = (unsigned short*)smem;
    const float cscl = (bn < 2) ? QSCL : 1.0f;
#pragma unroll
    for (int fn = 0; fn < 4; ++fn)
#pragma unroll
      for (int fm = 0; fm < 4; ++fm) {
        u16x4 pk;
#pragma unroll
        for (int r = 0; r < 4; ++r) pk[r] = f2bf(acc[fn][fm][r] * cscl);
        const int m = wm + fm * 16 + lo, n0 = wn + fn * 16 + hi * 4;
        *(u16x4*)(cs + m * 136 + n0) = pk;
      }
    __syncthreads();
    unsigned short* dstmat = (bn < 2) ? qo : (bn < 4) ? ko : vo;
    const int colbase = (bn & 1) * 128;
#pragma unroll
    for (int p = 0; p < 8; ++p) {
      const int ml = p * 16 + (tid >> 4), n0 = (tid & 15) * 8;
      u16x8 v = *(u16x8*)(cs + ml * 136 + n0);
      const int c = colbase + n0, h = c >> 6, hd = c & 63;
      const long m = arow0 + ml;
      const int b = (int)(m >> 12), s = (int)(m & 4095);
      *(u16x8*)(dstmat + ((long)(b * HN + h) * SN + s) * HD + hd) = v;
    }
  } else {
    float* csf = (float*)smem;
#pragma unroll
    for (int fn = 0; fn < 4; ++fn)
#pragma unroll
      for (int fm = 0; fm < 4; ++fm) {
        const int m = wm + fm * 16 + lo, n0 = wn + fn * 16 + hi * 4;
        *(f32x4*)(csf + m * 132 + n0) = acc[fn][fm];
      }
    __syncthreads();
#pragma unroll
    for (int p = 0; p < 8; ++p) {
      const int ml = p * 16 + (tid >> 4), n0 = (tid & 15) * 8;
      f32x4 v0 = *(f32x4*)(csf + ml * 132 + n0);
      f32x4 v1 = *(f32x4*)(csf + ml * 132 + n0 + 4);
      float* dst = out + (arow0 + ml) * DN + bn * 128 + n0;
      *(f32x4*)dst = v0;
      *(f32x4*)(dst + 4) = v1;
    }
  }
}

// ---------------- flash attention, causal, KVB=64, exp2-domain softmax,
// K prefetched into registers, XOR-swizzled V^T and P in LDS.
__global__ __launch_bounds__(256) void attn_kernel(
    const unsigned short* __restrict__ Qw, const unsigned short* __restrict__ Kw,
    const unsigned short* __restrict__ Vw, unsigned short* __restrict__ Ow) {
  // VT: V^T tile, rows = hd (0..63), cols = key (0..63), double-buffered.
  // swizzle: ushort idx = row*64 + (col ^ ((row&7)<<3))
  __shared__ __align__(16) unsigned short VTl[2][4096];
  // Pl: per-wave P tile, rows = q lane lo, cols = key. same swizzle.
  __shared__ __align__(16) unsigned short Plf[4][1024];

  const int tid = threadIdx.x;
  const int w = tid >> 6, lane = tid & 63;
  const int lo = lane & 15, hi = lane >> 4;
  const int bid = blockIdx.x;
  const int bh = bid & 15;
  const int qb = 63 - (bid >> 4);          // heavy q-blocks dispatched first
  const int q0 = qb * 64;
  const int qw = q0 + w * 16;
  const long base = (long)bh * SN * HD;
  const int nt = qb + 1;

  // Q fragments (B-operand: col=lo -> q row, k = hd); Q pre-scaled by QSCL
  short8 qf[2];
#pragma unroll
  for (int c = 0; c < 2; ++c)
    qf[c] = *(const short8*)(Qw + base + (long)(qw + lo) * HD + c * 32 + hi * 8);

  // K fragments, single rotating register buffer (reused after QK^T)
  short8 kb[8];
  auto loadK = [&](int k0) {
#pragma unroll
    for (int tt = 0; tt < 4; ++tt)
#pragma unroll
      for (int c = 0; c < 2; ++c)
        kb[tt * 2 + c] = *(const short8*)(Kw + base +
            (long)(k0 + tt * 16 + lo) * HD + c * 32 + hi * 8);
  };

  // V staging: thread owns key pair (k0t,k0t+1) x hd rows [h0t,h0t+8)
  const int k0t = 2 * (tid & 31);
  const int h0t = 8 * (tid >> 5);
  short8 va, vb2;
  auto loadV = [&](int k0) {
    const unsigned short* vp = Vw + base + (long)(k0 + k0t) * HD + h0t;
    va  = *(const short8*)vp;
    vb2 = *(const short8*)(vp + HD);
  };
  auto storeV = [&](int buf) {
#pragma unroll
    for (int j = 0; j < 8; ++j) {
      unsigned int pk = (unsigned int)(unsigned short)va[j] |
                        ((unsigned int)(unsigned short)vb2[j] << 16);
      *(unsigned int*)&VTl[buf][(h0t + j) * 64 + (k0t ^ (j << 3))] = pk;
    }
  };

  f32x4 oacc[4];  // [n]: O[q=qw+4*hi+r][hd=n*16+lo]
#pragma unroll
  for (int n = 0; n < 4; ++n)
#pragma unroll
    for (int e = 0; e < 4; ++e) oacc[n][e] = 0.f;
  float m_ = -INFINITY, l_ = 0.f;  // softmax state for q = qw+lo (log2 domain)

  loadK(0);
  loadV(0);
  storeV(0);
  __syncthreads();

  for (int kt = 0; kt < nt; ++kt) {
    const int cur = kt & 1;
    const int k0 = kt * KVB;

    // ---- QK^T swapped: sc[tt] C[row=key 16tt+4hi+r][col=q lo] (log2 domain)
    f32x4 sc[4];
#pragma unroll
    for (int tt = 0; tt < 4; ++tt)
#pragma unroll
      for (int e = 0; e < 4; ++e) sc[tt][e] = 0.f;
#pragma unroll
    for (int tt = 0; tt < 4; ++tt)
#pragma unroll
      for (int c = 0; c < 2; ++c)
        sc[tt] = __builtin_amdgcn_mfma_f32_16x16x32_bf16(
            kb[tt * 2 + c], qf[c], sc[tt], 0, 0, 0);

    // ---- prefetch next tile's K (regs now dead) and V (global->reg)
    if (kt + 1 < nt) { loadK(k0 + KVB); loadV(k0 + KVB); }

    // ---- causal mask (only the last tile straddles the diagonal)
    if (kt + 1 == nt) {
      const int kbase = k0 + 4 * hi - qw - lo;  // key - q = kbase + 16tt + r
#pragma unroll
      for (int tt = 0; tt < 4; ++tt)
#pragma unroll
        for (int r = 0; r < 4; ++r)
          if (kbase + 16 * tt + r > 0) sc[tt][r] = -INFINITY;
    }

    // ---- row max (q row = lanes {lo,lo+16,lo+32,lo+48})
    float mx;
    {
      f32x4 m4 = sc[0];
#pragma unroll
      for (int tt = 1; tt < 4; ++tt)
#pragma unroll
        for (int r = 0; r < 4; ++r) m4[r] = fmaxf(m4[r], sc[tt][r]);
      mx = fmaxf(fmaxf(m4[0], m4[1]), fmaxf(m4[2], m4[3]));
      mx = fmaxf(mx, __shfl_xor(mx, 16, 64));
      mx = fmaxf(mx, __shfl_xor(mx, 32, 64));
    }

    // ---- defer-max (T13): rescale only when max grew materially
    if (__any(mx > m_ + 8.f)) {
      const float mn = fmaxf(m_, mx);
      const float alpha = __builtin_amdgcn_exp2f(m_ - mn);
      m_ = mn;
      l_ *= alpha;
#pragma unroll
      for (int r = 0; r < 4; ++r) {
        const float ar = __shfl(alpha, 4 * hi + r, 64);
#pragma unroll
        for (int n = 0; n < 4; ++n) oacc[n][r] *= ar;
      }
    }

    // ---- exp2 + row sum (p overwrites sc)
    float rs = 0.f;
#pragma unroll
    for (int tt = 0; tt < 4; ++tt)
#pragma unroll
      for (int r = 0; r < 4; ++r) {
        const float e = __builtin_amdgcn_exp2f(sc[tt][r] - m_);
        sc[tt][r] = e;
        rs += e;
      }
    rs += __shfl_xor(rs, 16, 64);
    rs += __shfl_xor(rs, 32, 64);
    l_ += rs;

    // ---- P -> LDS (bf16, swizzled uint2 writes)
#pragma unroll
    for (int tt = 0; tt < 4; ++tt) {
      const unsigned int w0 = cvt_pk_bf16(sc[tt][0], sc[tt][1]);
      const unsigned int w1 = cvt_pk_bf16(sc[tt][2], sc[tt][3]);
      *(uint2*)&Plf[w][lo * 64 + ((tt * 16 + hi * 4) ^ ((lo & 7) << 3))] =
          make_uint2(w0, w1);
    }
    asm volatile("s_waitcnt lgkmcnt(0)" ::: "memory");

    // ---- PV: O += P[16q x 64k] * V^T (swizzled reads, conflict-free)
#pragma unroll
    for (int c = 0; c < 2; ++c) {
      const int sw = (c * 32 + hi * 8) ^ ((lo & 7) << 3);
      short8 pa = *(const short8*)&Plf[w][lo * 64 + sw];
#pragma unroll
      for (int n = 0; n < 4; ++n) {
        short8 vbf = *(const short8*)&VTl[cur][(n * 16 + lo) * 64 + sw];
        oacc[n] = __builtin_amdgcn_mfma_f32_16x16x32_bf16(pa, vbf, oacc[n], 0, 0, 0);
      }
    }

    // ---- stage next V tile into the other buffer
    if (kt + 1 < nt) storeV(cur ^ 1);
    __syncthreads();
  }

  // ---- epilogue
  const float rl = 1.f / l_;
  const int b = bh >> 2, h = bh & 3;
#pragma unroll
  for (int r = 0; r < 4; ++r) {
    const float rr = __shfl(rl, 4 * hi + r, 64);
    const int q = qw + 4 * hi + r;
#pragma unroll
    for (int n = 0; n < 4; ++n)
      Ow[((long)(b * SN + q)) * DN + h * HD + n * 16 + lo] = f2bf(oacc[n][r] * rr);
  }
}

extern "C" void kernel_launch(void* const* d_in, const int* in_sizes, int n_in,
                              void* d_out, int out_size, void* d_ws, size_t ws_size,
                              hipStream_t stream) {
  const float* x  = (const float*)d_in[0];
  const float* Wq = (const float*)d_in[1];
  const float* Wk = (const float*)d_in[2];
  const float* Wv = (const float*)d_in[3];
  const float* Wo = (const float*)d_in[4];
  float* out = (float*)d_out;

  const size_t per = (size_t)MROWS * DN;
  unsigned short* xb   = (unsigned short*)d_ws;
  unsigned short* Wcat = xb + per;
  unsigned short* Wob  = Wcat + 768 * 256;
  unsigned short* Qw   = Wob + 65536;
  unsigned short* Kw   = Qw + per;
  unsigned short* Vw   = Kw + per;
  unsigned short* Ow   = xb;  // alias: xb dead after qkv gemm

  convert_kernel<<<2048, 256, 0, stream>>>(x, Wq, Wk, Wv, Wo, xb, Wcat, Wob);
  gemm_kernel<0, 6><<<6 * (MROWS / 128), 256, 0, stream>>>(
      xb, Wcat, Qw, Kw, Vw, nullptr);
  attn_kernel<<<(BN * HN) * (SN / 64), 256, 0, stream>>>(Qw, Kw, Vw, Ow);
  gemm_kernel<1, 2><<<2 * (MROWS / 128), 256, 0, stream>>>(
      Ow, Wob, nullptr, nullptr, nullptr, out);
}

// Round 5
// 155.476 us; speedup vs baseline: 4.4658x; 1.2757x over previous
//
#include <hip/hip_runtime.h>
#include <hip/hip_bf16.h>
#include <cstdint>

using short8  = __attribute__((ext_vector_type(8))) short;
using u16x8   = __attribute__((ext_vector_type(8))) unsigned short;
using u16x4   = __attribute__((ext_vector_type(4))) unsigned short;
using f32x4   = __attribute__((ext_vector_type(4))) float;
using f32x16  = __attribute__((ext_vector_type(16))) float;

constexpr int BN = 4, HN = 4, SN = 4096, DN = 256, HD = 64;
constexpr int MROWS = BN * SN;  // 16384
// Q pre-scale: (1/sqrt(64)) * log2(e) -> scores land in exp2 domain
constexpr float QSCL = 0.18033688011112042f;

__device__ __forceinline__ unsigned short f2bf(float x) {
  union { float f; unsigned int u; } c; c.f = x;
  unsigned int u = c.u;
  return (unsigned short)((u + 0x7fffu + ((u >> 16) & 1u)) >> 16);
}
__device__ __forceinline__ unsigned int cvt_pk_bf16(float a, float b) {
  unsigned int r;
  asm("v_cvt_pk_bf16_f32 %0, %1, %2" : "=v"(r) : "v"(a), "v"(b));
  return r;  // low16 = bf16(a), high16 = bf16(b)
}
// After: a = [a(l<32) | b(l<32)], b = [a(l>=32) | b(l>=32)]
__device__ __forceinline__ void pl32swap(unsigned int& a, unsigned int& b) {
  asm volatile("v_permlane32_swap_b32 %0, %1" : "+v"(a), "+v"(b));
}

#define GLDS16(g, l)                                                  \
  __builtin_amdgcn_global_load_lds(                                   \
      (const __attribute__((address_space(1))) void*)(g),             \
      (__attribute__((address_space(3))) void*)(l), 16, 0, 0)

// ---------------- fp32 -> bf16 conversion: x, Wq|Wk|Wv (concat), Wo
__global__ __launch_bounds__(256) void convert_kernel(
    const float* __restrict__ x,  const float* __restrict__ Wq,
    const float* __restrict__ Wk, const float* __restrict__ Wv,
    const float* __restrict__ Wo,
    unsigned short* __restrict__ xb, unsigned short* __restrict__ Wcat,
    unsigned short* __restrict__ Wob) {
  const long NX4 = (long)MROWS * DN / 4;
  const long NW4 = 65536 / 4;
  const long total = NX4 + 4 * NW4;
  for (long i = (long)blockIdx.x * 256 + threadIdx.x; i < total;
       i += (long)gridDim.x * 256) {
    const float* src; unsigned short* dst;
    if (i < NX4) { src = x + i * 4; dst = xb + i * 4; }
    else {
      long j = i - NX4; int w = (int)(j >> 14); long o = (j & 16383) * 4;
      src = (w == 0 ? Wq : w == 1 ? Wk : w == 2 ? Wv : Wo) + o;
      dst = (w < 3 ? Wcat + (long)w * 65536 : Wob) + o;
    }
    float4 v = *(const float4*)src;
    u16x4 pk; pk[0] = f2bf(v.x); pk[1] = f2bf(v.y);
    pk[2] = f2bf(v.z); pk[3] = f2bf(v.w);
    *(u16x4*)dst = pk;
  }
}

// ---------------- bf16 MFMA GEMM: C[M][N] = A[M][K=256] * B[N][K=256]^T
// MODE 0: write q(*QSCL)/k/v bf16 [B,H,S,HD]; MODE 1: write fp32 [M][256].
template <int MODE, int NBN>
__global__ __launch_bounds__(256) void gemm_kernel(
    const unsigned short* __restrict__ Abf,
    const unsigned short* __restrict__ Bbf,
    unsigned short* __restrict__ qo, unsigned short* __restrict__ ko,
    unsigned short* __restrict__ vo, float* __restrict__ out) {
  constexpr int SMEM = (MODE == 1) ? 128 * 132 * 4 : 128 * 136 * 2;
  __shared__ __align__(16) char smem[SMEM];
  unsigned short* stg = (unsigned short*)smem;

  const int tid = threadIdx.x, lane = tid & 63, wid = tid >> 6;
  const int lo = lane & 15, hi = lane >> 4;
  const int bn = blockIdx.x % NBN, bm = blockIdx.x / NBN;
  const int wm = (wid >> 1) * 64, wn = (wid & 1) * 64;
  const long arow0 = (long)bm * 128, brow0 = (long)bn * 128;

  auto stage = [&](int buf, int kt) {
    const int row = (wid * 2) * 16 + (lane >> 2);
    const int col = (lane & 3) * 8;
    const unsigned short* ga = Abf + (arow0 + row) * DN + kt * 32 + col;
    const unsigned short* gb = Bbf + (brow0 + row) * DN + kt * 32 + col;
    unsigned short* la = stg + buf * 8192 + wid * 1024;
    unsigned short* lb = la + 4096;
    GLDS16(ga, la);
    GLDS16(ga + 16 * DN, la + 512);
    GLDS16(gb, lb);
    GLDS16(gb + 16 * DN, lb + 512);
  };

  f32x4 acc[4][4];
#pragma unroll
  for (int a = 0; a < 4; ++a)
#pragma unroll
    for (int b = 0; b < 4; ++b)
#pragma unroll
      for (int e = 0; e < 4; ++e) acc[a][b][e] = 0.f;

  stage(0, 0);
#pragma unroll
  for (int kt = 0; kt < 8; ++kt) {
    const int buf = kt & 1;
    __syncthreads();
    if (kt < 7) stage(buf ^ 1, kt + 1);
    const unsigned short* sa = stg + buf * 8192;
    const unsigned short* sb = sa + 4096;
    short8 af[4], bf[4];
#pragma unroll
    for (int f = 0; f < 4; ++f) {
      af[f] = *(const short8*)(sa + (wm + f * 16 + lo) * 32 + hi * 8);
      bf[f] = *(const short8*)(sb + (wn + f * 16 + lo) * 32 + hi * 8);
    }
#pragma unroll
    for (int fn = 0; fn < 4; ++fn)
#pragma unroll
      for (int fm = 0; fm < 4; ++fm)
        acc[fn][fm] = __builtin_amdgcn_mfma_f32_16x16x32_bf16(
            bf[fn], af[fm], acc[fn][fm], 0, 0, 0);
  }
  __syncthreads();

  if constexpr (MODE == 0) {
    unsigned short* cs = (unsigned short*)smem;
    const float cscl = (bn < 2) ? QSCL : 1.0f;
#pragma unroll
    for (int fn = 0; fn < 4; ++fn)
#pragma unroll
      for (int fm = 0; fm < 4; ++fm) {
        u16x4 pk;
#pragma unroll
        for (int r = 0; r < 4; ++r) pk[r] = f2bf(acc[fn][fm][r] * cscl);
        const int m = wm + fm * 16 + lo, n0 = wn + fn * 16 + hi * 4;
        *(u16x4*)(cs + m * 136 + n0) = pk;
      }
    __syncthreads();
    unsigned short* dstmat = (bn < 2) ? qo : (bn < 4) ? ko : vo;
    const int colbase = (bn & 1) * 128;
#pragma unroll
    for (int p = 0; p < 8; ++p) {
      const int ml = p * 16 + (tid >> 4), n0 = (tid & 15) * 8;
      u16x8 v = *(u16x8*)(cs + ml * 136 + n0);
      const int c = colbase + n0, h = c >> 6, hd = c & 63;
      const long m = arow0 + ml;
      const int b = (int)(m >> 12), s = (int)(m & 4095);
      *(u16x8*)(dstmat + ((long)(b * HN + h) * SN + s) * HD + hd) = v;
    }
  } else {
    float* csf = (float*)smem;
#pragma unroll
    for (int fn = 0; fn < 4; ++fn)
#pragma unroll
      for (int fm = 0; fm < 4; ++fm) {
        const int m = wm + fm * 16 + lo, n0 = wn + fn * 16 + hi * 4;
        *(f32x4*)(csf + m * 132 + n0) = acc[fn][fm];
      }
    __syncthreads();
#pragma unroll
    for (int p = 0; p < 8; ++p) {
      const int ml = p * 16 + (tid >> 4), n0 = (tid & 15) * 8;
      f32x4 v0 = *(f32x4*)(csf + ml * 132 + n0);
      f32x4 v1 = *(f32x4*)(csf + ml * 132 + n0 + 4);
      float* dst = out + (arow0 + ml) * DN + bn * 128 + n0;
      *(f32x4*)dst = v0;
      *(f32x4*)(dst + 4) = v1;
    }
  }
}

// ---------------- flash attention, causal. 32x32 MFMA, in-register softmax.
// Block = 4 waves x 32 q rows = 128 q. Wave's lane l: q = qw + (l&31).
// QK^T: mfma(K,Q) -> C[key][q]; PV: mfma(V^T,P) -> C[hd][q].
__global__ __launch_bounds__(256) void attn_kernel(
    const unsigned short* __restrict__ Qw, const unsigned short* __restrict__ Kw,
    const unsigned short* __restrict__ Vw, unsigned short* __restrict__ Ow) {
  // V^T tiles: [hd 0..63][key 0..63], ushort idx = hd*64 + (key ^ ((hd&7)<<3))
  // Reused as O-transpose buffer (4 waves x [32 q][64 hd]) in the epilogue.
  __shared__ __align__(16) unsigned short VTl[2][4096];

  const int tid = threadIdx.x;
  const int w = tid >> 6, lane = tid & 63;
  const int l31 = lane & 31, h5 = lane >> 5;
  const int bid = blockIdx.x;
  const int bh = bid & 15;
  const int qb = 31 - (bid >> 4);          // heavy q-blocks dispatched first
  const int q0 = qb * 128;
  const int qw = q0 + w * 32;
  const long base = (long)bh * SN * HD;
  const int nt = 2 * qb + 2;               // KV tiles of 64 keys
  const int ktlast = qw >> 6;              // wave's last (masked) tile

  // Q frags (B-operand): lane holds Q[qw+l31][16ks + 8*h5 + j]
  short8 qf[4];
#pragma unroll
  for (int ks = 0; ks < 4; ++ks)
    qf[ks] = *(const short8*)(Qw + base + (long)(qw + l31) * HD + ks * 16 + h5 * 8);

  // K frags (A-operand): kb[s*4+ks] = K[k0+32s+l31][16ks + 8*h5 + j]
  short8 kb[8];
  auto loadK = [&](int k0) {
#pragma unroll
    for (int s = 0; s < 2; ++s)
#pragma unroll
      for (int ks = 0; ks < 4; ++ks)
        kb[s * 4 + ks] = *(const short8*)(Kw + base +
            (long)(k0 + 32 * s + l31) * HD + ks * 16 + h5 * 8);
  };

  // V staging: thread owns key pair (k0t,k0t+1) x hd rows [h0t,h0t+8)
  const int k0t = 2 * (tid & 31);
  const int h0t = 8 * (tid >> 5);
  short8 va8, vb8;
  auto loadV = [&](int k0) {
    const unsigned short* vp = Vw + base + (long)(k0 + k0t) * HD + h0t;
    va8 = *(const short8*)vp;
    vb8 = *(const short8*)(vp + HD);
  };
  auto storeV = [&](int buf) {
#pragma unroll
    for (int j = 0; j < 8; ++j) {
      unsigned int pk = (unsigned int)(unsigned short)va8[j] |
                        ((unsigned int)(unsigned short)vb8[j] << 16);
      *(unsigned int*)&VTl[buf][(h0t + j) * 64 + (k0t ^ (j << 3))] = pk;
    }
  };

  f32x16 oacc[2];  // [oh]: O[hd=32*oh+crow(r,h5)][q=l31]
#pragma unroll
  for (int oh = 0; oh < 2; ++oh)
#pragma unroll
    for (int r = 0; r < 16; ++r) oacc[oh][r] = 0.f;
  float m_ = -INFINITY, l_ = 0.f;  // per-lane softmax state for q = qw+l31

  loadK(0);
  loadV(0);
  storeV(0);
  __syncthreads();

  for (int kt = 0; kt < nt; ++kt) {
    const int cur = kt & 1;
    const int k0 = kt * 64;
    if (kt + 1 < nt) loadV(k0 + 64);  // global -> regs, hides under compute

    if (kt <= ktlast) {
      // ---- QK^T: sc[s] C[key=32s+crow(r,h5)][q=l31], log2 domain
      f32x16 sc0, sc1;
#pragma unroll
      for (int r = 0; r < 16; ++r) { sc0[r] = 0.f; sc1[r] = 0.f; }
#pragma unroll
      for (int ks = 0; ks < 4; ++ks)
        sc0 = __builtin_amdgcn_mfma_f32_32x32x16_bf16(kb[ks], qf[ks], sc0, 0, 0, 0);
#pragma unroll
      for (int ks = 0; ks < 4; ++ks)
        sc1 = __builtin_amdgcn_mfma_f32_32x32x16_bf16(kb[4 + ks], qf[ks], sc1, 0, 0, 0);

      // prefetch next K while kb regs are dead
      if (kt + 1 <= ktlast) loadK(k0 + 64);

      // V^T frags for PV (VTl[cur] ready since last barrier) - early ds_reads
      short8 va0[4], va1[4];
      const int vsw = (l31 & 7) << 3;
#pragma unroll
      for (int ks = 0; ks < 4; ++ks) {
        const int col = (16 * ks + 8 * h5) ^ vsw;
        va0[ks] = *(const short8*)&VTl[cur][l31 * 64 + col];
        va1[ks] = *(const short8*)&VTl[cur][(32 + l31) * 64 + col];
      }

      // ---- causal mask (only the wave's last tile straddles the diagonal)
      if (kt == ktlast) {
        const int mb0 = k0 + 4 * h5 - qw - l31;  // key - q for s=0, r=0
#pragma unroll
        for (int r = 0; r < 16; ++r) {
          const int d = (r & 3) + 8 * (r >> 2);
          if (mb0 + d > 0)      sc0[r] = -INFINITY;
          if (mb0 + 32 + d > 0) sc1[r] = -INFINITY;
        }
      }

      // ---- row max: in-reg tree + one cross-half exchange
      float mv[16];
#pragma unroll
      for (int r = 0; r < 16; ++r) mv[r] = fmaxf(sc0[r], sc1[r]);
#pragma unroll
      for (int st = 8; st >= 1; st >>= 1)
#pragma unroll
        for (int i = 0; i < st; ++i) mv[i] = fmaxf(mv[i], mv[i + st]);
      const float mx = fmaxf(mv[0], __shfl_xor(mv[0], 32, 64));

      // ---- defer-max (T13): rescale only when max grew materially
      if (__any(mx > m_ + 11.5f)) {
        const float mn = fmaxf(m_, mx);
        const float alpha = __builtin_amdgcn_exp2f(m_ - mn);
        m_ = mn;
        l_ *= alpha;
#pragma unroll
        for (int oh = 0; oh < 2; ++oh)
#pragma unroll
          for (int r = 0; r < 16; ++r) oacc[oh][r] *= alpha;
      }

      // ---- exp2 + row sum
#pragma unroll
      for (int r = 0; r < 16; ++r) {
        sc0[r] = __builtin_amdgcn_exp2f(sc0[r] - m_);
        sc1[r] = __builtin_amdgcn_exp2f(sc1[r] - m_);
      }
      float sv[16];
#pragma unroll
      for (int r = 0; r < 16; ++r) sv[r] = sc0[r] + sc1[r];
#pragma unroll
      for (int st = 8; st >= 1; st >>= 1)
#pragma unroll
        for (int i = 0; i < st; ++i) sv[i] += sv[i + st];
      float rs = sv[0];
      rs += __shfl_xor(rs, 32, 64);
      l_ += rs;

      // ---- P (B-operand) in-register via cvt_pk + permlane32_swap (T12)
      short8 pb[4];
#pragma unroll
      for (int s = 0; s < 2; ++s)
#pragma unroll
        for (int u = 0; u < 2; ++u) {
          unsigned int a0, a1, b0, b1;
          if (s == 0) {
            a0 = cvt_pk_bf16(sc0[8 * u + 0], sc0[8 * u + 1]);
            a1 = cvt_pk_bf16(sc0[8 * u + 2], sc0[8 * u + 3]);
            b0 = cvt_pk_bf16(sc0[8 * u + 4], sc0[8 * u + 5]);
            b1 = cvt_pk_bf16(sc0[8 * u + 6], sc0[8 * u + 7]);
          } else {
            a0 = cvt_pk_bf16(sc1[8 * u + 0], sc1[8 * u + 1]);
            a1 = cvt_pk_bf16(sc1[8 * u + 2], sc1[8 * u + 3]);
            b0 = cvt_pk_bf16(sc1[8 * u + 4], sc1[8 * u + 5]);
            b1 = cvt_pk_bf16(sc1[8 * u + 6], sc1[8 * u + 7]);
          }
          pl32swap(a0, b0);  // a0 -> frag word0, b0 -> frag word2
          pl32swap(a1, b1);  // a1 -> frag word1, b1 -> frag word3
          union { unsigned int u4[4]; short8 v; } pu;
          pu.u4[0] = a0; pu.u4[1] = a1; pu.u4[2] = b0; pu.u4[3] = b1;
          pb[s * 2 + u] = pu.v;
        }

      // ---- PV: oacc[oh] += V^T * P
#pragma unroll
      for (int ks = 0; ks < 4; ++ks) {
        oacc[0] = __builtin_amdgcn_mfma_f32_32x32x16_bf16(va0[ks], pb[ks], oacc[0], 0, 0, 0);
        oacc[1] = __builtin_amdgcn_mfma_f32_32x32x16_bf16(va1[ks], pb[ks], oacc[1], 0, 0, 0);
      }
    }

    // ---- stage next V tile into the other buffer
    if (kt + 1 < nt) storeV(cur ^ 1);
    __syncthreads();
  }

  // ---- epilogue: transpose O through LDS for coalesced stores
  unsigned short* ob = (unsigned short*)VTl;  // 4 waves x [32 q][64 hd]
  const float rl = 1.f / l_;
#pragma unroll
  for (int oh = 0; oh < 2; ++oh)
#pragma unroll
    for (int rq = 0; rq < 4; ++rq) {
      const int hdb = 32 * oh + 8 * rq + 4 * h5;
      const unsigned int u0 = cvt_pk_bf16(oacc[oh][4 * rq + 0] * rl,
                                          oacc[oh][4 * rq + 1] * rl);
      const unsigned int u1 = cvt_pk_bf16(oacc[oh][4 * rq + 2] * rl,
                                          oacc[oh][4 * rq + 3] * rl);
      *(uint2*)&ob[w * 2048 + l31 * 64 + (hdb ^ ((l31 & 7) << 3))] =
          make_uint2(u0, u1);
    }
  __syncthreads();
  const int b = bh >> 2, h = bh & 3;
#pragma unroll
  for (int pass = 0; pass < 4; ++pass) {
    const int rblk = pass * 32 + (tid >> 3);   // 0..127
    const int wreg = rblk >> 5, qi = rblk & 31;
    const int j = tid & 7;
    u16x8 vv = *(u16x8*)&ob[wreg * 2048 + qi * 64 + ((j * 8) ^ ((qi & 7) << 3))];
    *(u16x8*)(Ow + ((long)(b * SN + q0 + rblk)) * DN + h * HD + j * 8) = vv;
  }
}

extern "C" void kernel_launch(void* const* d_in, const int* in_sizes, int n_in,
                              void* d_out, int out_size, void* d_ws, size_t ws_size,
                              hipStream_t stream) {
  const float* x  = (const float*)d_in[0];
  const float* Wq = (const float*)d_in[1];
  const float* Wk = (const float*)d_in[2];
  const float* Wv = (const float*)d_in[3];
  const float* Wo = (const float*)d_in[4];
  float* out = (float*)d_out;

  const size_t per = (size_t)MROWS * DN;
  unsigned short* xb   = (unsigned short*)d_ws;
  unsigned short* Wcat = xb + per;
  unsigned short* Wob  = Wcat + 768 * 256;
  unsigned short* Qw   = Wob + 65536;
  unsigned short* Kw   = Qw + per;
  unsigned short* Vw   = Kw + per;
  unsigned short* Ow   = xb;  // alias: xb dead after qkv gemm

  convert_kernel<<<2048, 256, 0, stream>>>(x, Wq, Wk, Wv, Wo, xb, Wcat, Wob);
  gemm_kernel<0, 6><<<6 * (MROWS / 128), 256, 0, stream>>>(
      xb, Wcat, Qw, Kw, Vw, nullptr);
  attn_kernel<<<(BN * HN) * (SN / 128), 256, 0, stream>>>(Qw, Kw, Vw, Ow);
  gemm_kernel<1, 2><<<2 * (MROWS / 128), 256, 0, stream>>>(
      Ow, Wob, nullptr, nullptr, nullptr, out);
}